// Round 4
// baseline (158.727 us; speedup 1.0000x reference)
//
#include <hip/hip_runtime.h>

// MultiHeadedTrilinearAttention, MI355X — round 4: f16 MFMA, LDS-free GEMMs.
// B=1, S=128, DIM=768, H=12, W=64. Softmax groups = contiguous 4096 scores
// (g = h*512 + v*4 + q>>5, verified passing R1-R3); outputs collapse to 48
// marginal sums per group.
// ws layout (bytes): Wt f16 [6][768][768] = 7,077,888 | vI,qI,aI f16 = 589,824
// | vpH,qpH,apH f16 = 589,824 | vo,qo,ao f32 = 1,179,648. Total ~9.4 MB.

#define DIM   768
#define SEQ   128
#define NH    12
#define HW    64
#define PROJ_ELEMS (SEQ * DIM)   // 98304
#define WELEMS     (DIM * DIM)   // 589824
#define QOUT_OFF   98304
#define AOUT_OFF   196608

typedef _Float16 f16x8 __attribute__((ext_vector_type(8)));
typedef float    f32x4 __attribute__((ext_vector_type(4)));

// ---------------- prep: transpose+convert weights, convert inputs ----------
// grid (12,12,7). z<6: 64x64 transpose tile of weight z into Wt[z] ([n][k] f16).
// z==6: convert v,q,a fp32 -> f16 row-major (144 blocks x 2048 elems).
__global__ __launch_bounds__(256) void prep_kernel(
    const float* __restrict__ v, const float* __restrict__ q, const float* __restrict__ a,
    const float* __restrict__ W0, const float* __restrict__ W1, const float* __restrict__ W2,
    const float* __restrict__ W3, const float* __restrict__ W4, const float* __restrict__ W5,
    _Float16* __restrict__ Wt,
    _Float16* __restrict__ vI, _Float16* __restrict__ qI, _Float16* __restrict__ aI)
{
    const int z = blockIdx.z;
    const int t = threadIdx.x;
    if (z < 6) {
        const float* W = (z == 0) ? W0 : (z == 1) ? W1 : (z == 2) ? W2
                       : (z == 3) ? W3 : (z == 4) ? W4 : W5;
        _Float16* WtM = Wt + z * WELEMS;
        __shared__ _Float16 T[64][72];
        const int k0 = blockIdx.x * 64;
        const int n0 = blockIdx.y * 64;
        const int c4 = (t & 15) * 4;
        #pragma unroll
        for (int p = 0; p < 4; ++p) {
            const int r = (t >> 4) + 16 * p;     // k-local
            f32x4 wv = *(const f32x4*)&W[(k0 + r) * DIM + n0 + c4];
            T[c4 + 0][r] = (_Float16)wv[0];
            T[c4 + 1][r] = (_Float16)wv[1];
            T[c4 + 2][r] = (_Float16)wv[2];
            T[c4 + 3][r] = (_Float16)wv[3];
        }
        __syncthreads();
        const int c2 = (t & 7) * 8;
        #pragma unroll
        for (int p = 0; p < 2; ++p) {
            const int r = (t >> 3) + 32 * p;     // n-local
            *(f16x8*)&WtM[(n0 + r) * DIM + k0 + c2] = *(const f16x8*)&T[r][c2];
        }
    } else {
        const int bid = blockIdx.x + 12 * blockIdx.y;  // 0..143
        const int mat = bid / 48;
        const int off = (bid - mat * 48) * 2048 + t * 8;
        const float* src = (mat == 0) ? v : (mat == 1) ? q : a;
        _Float16* dst    = (mat == 0) ? vI : (mat == 1) ? qI : aI;
        f32x4 lo = *(const f32x4*)&src[off];
        f32x4 hi = *(const f32x4*)&src[off + 4];
        f16x8 o;
        o[0] = (_Float16)lo[0]; o[1] = (_Float16)lo[1];
        o[2] = (_Float16)lo[2]; o[3] = (_Float16)lo[3];
        o[4] = (_Float16)hi[0]; o[5] = (_Float16)hi[1];
        o[6] = (_Float16)hi[2]; o[7] = (_Float16)hi[3];
        *(f16x8*)&dst[off] = o;
    }
}

// ---------------- projection GEMM: LDS-free f16 MFMA ----------------
// C[128,768] = A[128,768]@W + b. A f16 row-major, W pre-transposed f16 [n][k].
// grid (24 n-tiles, 3 matrices); wave w handles rows [32w,32w+32), N=32/block.
__global__ __launch_bounds__(256) void proj_kernel(
    const _Float16* __restrict__ A0, const _Float16* __restrict__ A1, const _Float16* __restrict__ A2,
    const _Float16* __restrict__ T0, const _Float16* __restrict__ T1, const _Float16* __restrict__ T2,
    const float* __restrict__ b0, const float* __restrict__ b1, const float* __restrict__ b2,
    void* __restrict__ C0, void* __restrict__ C1, void* __restrict__ C2,
    int out_f16)
{
    const int mat = blockIdx.y;
    const _Float16* __restrict__ A = (mat == 0) ? A0 : (mat == 1) ? A1 : A2;
    const _Float16* __restrict__ T = (mat == 0) ? T0 : (mat == 1) ? T1 : T2;
    const float* __restrict__ bb   = (mat == 0) ? b0 : (mat == 1) ? b1 : b2;
    void* __restrict__ C           = (mat == 0) ? C0 : (mat == 1) ? C1 : C2;

    const int n0   = blockIdx.x * 32;
    const int t    = threadIdx.x;
    const int w    = t >> 6;
    const int lane = t & 63;
    const int fm   = lane & 15;
    const int fk   = (lane >> 4) << 3;

    const _Float16* pa0 = A + (32 * w + fm) * DIM + fk;
    const _Float16* pa1 = pa0 + 16 * DIM;
    const _Float16* pb0 = T + (n0 + fm) * DIM + fk;
    const _Float16* pb1 = pb0 + 16 * DIM;

    f32x4 acc[2][2];
    #pragma unroll
    for (int i = 0; i < 2; ++i)
        #pragma unroll
        for (int j = 0; j < 2; ++j) acc[i][j] = (f32x4){0.f, 0.f, 0.f, 0.f};

    #pragma unroll 4
    for (int s = 0; s < 24; ++s) {
        const f16x8 a0 = *(const f16x8*)(pa0 + 32 * s);
        const f16x8 a1 = *(const f16x8*)(pa1 + 32 * s);
        const f16x8 w0 = *(const f16x8*)(pb0 + 32 * s);
        const f16x8 w1 = *(const f16x8*)(pb1 + 32 * s);
        acc[0][0] = __builtin_amdgcn_mfma_f32_16x16x32_f16(a0, w0, acc[0][0], 0, 0, 0);
        acc[0][1] = __builtin_amdgcn_mfma_f32_16x16x32_f16(a0, w1, acc[0][1], 0, 0, 0);
        acc[1][0] = __builtin_amdgcn_mfma_f32_16x16x32_f16(a1, w0, acc[1][0], 0, 0, 0);
        acc[1][1] = __builtin_amdgcn_mfma_f32_16x16x32_f16(a1, w1, acc[1][1], 0, 0, 0);
    }

    const int quad4 = (lane >> 4) << 2;
    #pragma unroll
    for (int mt = 0; mt < 2; ++mt) {
        const int row0 = 32 * w + 16 * mt + quad4;
        #pragma unroll
        for (int nt = 0; nt < 2; ++nt) {
            const int col = n0 + 16 * nt + fm;
            const float bi = bb[col];
            #pragma unroll
            for (int rr = 0; rr < 4; ++rr) {
                const float val = acc[mt][nt][rr] + bi;
                if (out_f16) ((_Float16*)C)[(row0 + rr) * DIM + col] = (_Float16)val;
                else         ((float*)C)[(row0 + rr) * DIM + col]    = val;
            }
        }
    }
}

// map flat index of (H,S,W)-ordered "heads view" back into row-major (S,DIM)
__device__ __forceinline__ float fetch_o(const float* __restrict__ p, int idx) {
    return p[((idx >> 6) & 127) * DIM + (idx >> 13) * HW + (idx & 63)];
}

// -------- fused MFMA scores + group softmax + marginals + outputs --------
// block = (v-token, head). S[q][a] = sum_k vq[q,k]*ah[a,k], f16 MFMA.
// wave w == softmax group (q in [32w,32w+32)). ah B-frags direct from global.
// C layout: col a = at*16+fm; row q'' = qt*16 + quad*4 + rr. No max-sub
// (scores ~N(0,0.17), |s|<~1.5 — exp safe).
__global__ __launch_bounds__(256) void fused_attn_kernel(
    const _Float16* __restrict__ vpH, const _Float16* __restrict__ qpH,
    const _Float16* __restrict__ apH,
    const float* __restrict__ vo, const float* __restrict__ qo, const float* __restrict__ ao,
    float* __restrict__ out)
{
    const int vtok = blockIdx.x;   // 0..127
    const int h    = blockIdx.y;   // 0..11

    __shared__ _Float16 vqL[128][72];  // [q][k] f16, pad 72

    const int t    = threadIdx.x;
    const int w    = t >> 6;
    const int lane = t & 63;
    const int fm   = lane & 15;
    const int fk   = (lane >> 4) << 3;

    // staging: thread t -> row r = t>>1, k-half kh = (t&1)*32
    {
        const int r  = t >> 1;
        const int kh = (t & 1) << 5;
        const _Float16* pq = qpH + r    * DIM + h * HW + kh;
        const _Float16* pv = vpH + vtok * DIM + h * HW + kh;
        #pragma unroll
        for (int u = 0; u < 4; ++u) {
            const f16x8 qv = *(const f16x8*)(pq + 8 * u);
            const f16x8 vv = *(const f16x8*)(pv + 8 * u);
            *(f16x8*)&vqL[r][kh + 8 * u] = qv * vv;   // v_pk_mul_f16
        }
    }
    __syncthreads();

    f32x4 acc[2][8];
    #pragma unroll
    for (int qt = 0; qt < 2; ++qt)
        #pragma unroll
        for (int at = 0; at < 8; ++at)
            acc[qt][at] = (f32x4){0.f, 0.f, 0.f, 0.f};

    const int q0 = 32 * w;
    #pragma unroll
    for (int ks = 0; ks < 2; ++ks) {
        const f16x8 af0 = *(const f16x8*)&vqL[q0 + fm     ][32 * ks + fk];
        const f16x8 af1 = *(const f16x8*)&vqL[q0 + 16 + fm][32 * ks + fk];
        #pragma unroll
        for (int at = 0; at < 8; ++at) {
            const f16x8 bf = *(const f16x8*)&apH[(16 * at + fm) * DIM + h * HW + 32 * ks + fk];
            acc[0][at] = __builtin_amdgcn_mfma_f32_16x16x32_f16(af0, bf, acc[0][at], 0, 0, 0);
            acc[1][at] = __builtin_amdgcn_mfma_f32_16x16x32_f16(af1, bf, acc[1][at], 0, 0, 0);
        }
    }

    // exp + marginal partials (no max subtraction).
    // q'' = qt*16 + quad*4 + rr ; a = at*16 + fm
    // v-bin = q''>>1 = qt*8 + quad*2 + (rr>>1) -> sv[qt][rr>>1] (quad in lane)
    // q-bin = (rr&1)*8 + at                    -> sq[rr&1][at]  (lane-uniform)
    // a-bin = fm                               -> sa            (fm in lane)
    float sv[2][2] = {{0.f, 0.f}, {0.f, 0.f}};
    float sq[2][8];
    #pragma unroll
    for (int i = 0; i < 2; ++i)
        #pragma unroll
        for (int j = 0; j < 8; ++j) sq[i][j] = 0.f;
    float sa = 0.f;
    #pragma unroll
    for (int qt = 0; qt < 2; ++qt)
        #pragma unroll
        for (int at = 0; at < 8; ++at)
            #pragma unroll
            for (int rr = 0; rr < 4; ++rr) {
                const float e = __expf(acc[qt][at][rr] * 0.125f);
                sv[qt][rr >> 1] += e;
                sq[rr & 1][at]  += e;
                sa += e;
            }

    // --- reductions (split butterflies, ~28 shfl total) ---
    // sa: bins = fm, reduce over quads
    sa += __shfl_xor(sa, 16);
    sa += __shfl_xor(sa, 32);
    // tot: sum of the 16 a-bins
    float tot = sa;
    tot += __shfl_xor(tot, 1);
    tot += __shfl_xor(tot, 2);
    tot += __shfl_xor(tot, 4);
    tot += __shfl_xor(tot, 8);
    // sv: split by qt (d=1), then rh (d=2), then accumulate (d=4,8)
    const bool b0 = lane & 1;
    const bool b1 = lane & 2;
    float sF;
    {
        float snd0 = b0 ? sv[0][0] : sv[1][0];
        float snd1 = b0 ? sv[0][1] : sv[1][1];
        float r0 = __shfl_xor(snd0, 1);
        float r1 = __shfl_xor(snd1, 1);
        float s0 = (b0 ? sv[1][0] : sv[0][0]) + r0;   // qt = b0, rh = 0
        float s1 = (b0 ? sv[1][1] : sv[0][1]) + r1;   // qt = b0, rh = 1
        float snd = b1 ? s0 : s1;
        float r2 = __shfl_xor(snd, 2);
        sF = (b1 ? s1 : s0) + r2;                     // qt = b0, rh = b1
    }
    sF += __shfl_xor(sF, 4);
    sF += __shfl_xor(sF, 8);
    // sq: split-butterfly 16 values over lane bits 0..3, then quad accumulate
    float s[16];
    #pragma unroll
    for (int i = 0; i < 2; ++i)
        #pragma unroll
        for (int j = 0; j < 8; ++j) s[i * 8 + j] = sq[i][j];
    #pragma unroll
    for (int k = 0; k < 4; ++k) {
        const int d = 1 << k;
        const int m = 16 >> (k + 1);
        const bool b = (lane >> k) & 1;
        #pragma unroll
        for (int x = 0; x < m; ++x) {
            const float snd = b ? s[x] : s[x + m];
            const float rcv = __shfl_xor(snd, d);
            s[x] = (b ? s[x + m] : s[x]) + rcv;
        }
    }
    s[0] += __shfl_xor(s[0], 16);
    s[0] += __shfl_xor(s[0], 32);
    // final: lane's q-bin = 8*b0 + 4*b1 + 2*b2 + b3 of its fm bits

    const int g  = h * 512 + vtok * 4 + w;    // softmax group id
    const int b2 = g / 12;
    const int h2 = g - b2 * 12;
    const float invZ = 1.0f / tot;

    if (fm < 4) {                             // 16 writer lanes: v-outputs
        const int quad = lane >> 4;
        const int bin  = (fm & 1) * 8 + quad * 2 + ((fm >> 1) & 1);
        out[(b2 * 16 + bin) * 12 + h2] = sF * invZ * fetch_o(vo, g * 16 + bin);
    }
    if (lane < 16) {                          // 16 writer lanes: q- and a-outputs
        const int qbin = 8 * (lane & 1) + 4 * ((lane >> 1) & 1)
                       + 2 * ((lane >> 2) & 1) + (lane >> 3);
        out[QOUT_OFF + (b2 * 16 + qbin) * 12 + h2] =
            s[0] * invZ * fetch_o(qo, g * 16 + qbin);
        out[AOUT_OFF + (b2 * 16 + lane) * 12 + h2] =
            sa * invZ * fetch_o(ao, g * 16 + lane);
    }
}

extern "C" void kernel_launch(void* const* d_in, const int* in_sizes, int n_in,
                              void* d_out, int out_size, void* d_ws, size_t ws_size,
                              hipStream_t stream)
{
    const float* v   = (const float*)d_in[0];
    const float* q   = (const float*)d_in[1];
    const float* a   = (const float*)d_in[2];
    // d_in[3..5] = masks, unused by the reference forward
    const float* Wv  = (const float*)d_in[6];
    const float* bv  = (const float*)d_in[7];
    const float* Wq  = (const float*)d_in[8];
    const float* bq  = (const float*)d_in[9];
    const float* Wa  = (const float*)d_in[10];
    const float* ba  = (const float*)d_in[11];
    const float* Wvo = (const float*)d_in[12];
    const float* bvo = (const float*)d_in[13];
    const float* Wqo = (const float*)d_in[14];
    const float* bqo = (const float*)d_in[15];
    const float* Wao = (const float*)d_in[16];
    const float* bao = (const float*)d_in[17];

    float* out = (float*)d_out;

    _Float16* Wt  = (_Float16*)d_ws;             // 6 * 589824 f16
    _Float16* vI  = Wt + 6 * WELEMS;
    _Float16* qI  = vI + PROJ_ELEMS;
    _Float16* aI  = qI + PROJ_ELEMS;
    _Float16* vpH = aI + PROJ_ELEMS;
    _Float16* qpH = vpH + PROJ_ELEMS;
    _Float16* apH = qpH + PROJ_ELEMS;
    float*    vo  = (float*)(apH + PROJ_ELEMS);
    float*    qo  = vo + PROJ_ELEMS;
    float*    ao  = qo + PROJ_ELEMS;

    // 1) transpose+convert weights to f16 [n][k]; convert inputs to f16
    prep_kernel<<<dim3(12, 12, 7), 256, 0, stream>>>(
        v, q, a, Wv, Wq, Wa, Wvo, Wqo, Wao, Wt, vI, qI, aI);
    // 2) stage-1 projections (f16 out)
    proj_kernel<<<dim3(24, 3), 256, 0, stream>>>(
        vI, qI, aI, Wt, Wt + WELEMS, Wt + 2 * WELEMS,
        bv, bq, ba, vpH, qpH, apH, 1);
    // 3) stage-2 projections (f32 out; consumed scalar-wise by fused epilogue)
    proj_kernel<<<dim3(24, 3), 256, 0, stream>>>(
        vpH, qpH, apH, Wt + 3 * WELEMS, Wt + 4 * WELEMS, Wt + 5 * WELEMS,
        bvo, bqo, bao, vo, qo, ao, 0);
    // 4) fused trilinear scores + grouped softmax + marginal outputs
    fused_attn_kernel<<<dim3(SEQ, NH), 256, 0, stream>>>(
        vpH, qpH, apH, vo, qo, ao, out);
}

// Round 5
// 137.116 us; speedup vs baseline: 1.1576x; 1.1576x over previous
//
#include <hip/hip_runtime.h>

// MultiHeadedTrilinearAttention, MI355X — round 5.
// f16 MFMA; fused kernel stages BOTH operands in LDS (R4's global B-frags
// serialized at ~900cyc/load, MfmaUtil 2%); proj uses 1-wave 16x16 tiles for
// max wave count (1152 blocks vs 72).
// ws layout: Wt f16 [6][768][768] | vI,qI,aI f16 | vpH,qpH,apH f16 | vo,qo,ao f32.

#define DIM   768
#define SEQ   128
#define NH    12
#define HW    64
#define PROJ_ELEMS (SEQ * DIM)   // 98304
#define WELEMS     (DIM * DIM)   // 589824
#define QOUT_OFF   98304
#define AOUT_OFF   196608

typedef _Float16 f16x8 __attribute__((ext_vector_type(8)));
typedef float    f32x4 __attribute__((ext_vector_type(4)));

// ---------------- prep: transpose+convert weights, convert inputs ----------
// grid (12,12,7). z<6: 64x64 transpose tile of weight z into Wt[z] ([n][k] f16).
// z==6: convert v,q,a fp32 -> f16 row-major (144 blocks x 2048 elems).
__global__ __launch_bounds__(256) void prep_kernel(
    const float* __restrict__ v, const float* __restrict__ q, const float* __restrict__ a,
    const float* __restrict__ W0, const float* __restrict__ W1, const float* __restrict__ W2,
    const float* __restrict__ W3, const float* __restrict__ W4, const float* __restrict__ W5,
    _Float16* __restrict__ Wt,
    _Float16* __restrict__ vI, _Float16* __restrict__ qI, _Float16* __restrict__ aI)
{
    const int z = blockIdx.z;
    const int t = threadIdx.x;
    if (z < 6) {
        const float* W = (z == 0) ? W0 : (z == 1) ? W1 : (z == 2) ? W2
                       : (z == 3) ? W3 : (z == 4) ? W4 : W5;
        _Float16* WtM = Wt + z * WELEMS;
        __shared__ _Float16 T[64][72];
        const int k0 = blockIdx.x * 64;
        const int n0 = blockIdx.y * 64;
        const int c4 = (t & 15) * 4;
        #pragma unroll
        for (int p = 0; p < 4; ++p) {
            const int r = (t >> 4) + 16 * p;     // k-local
            f32x4 wv = *(const f32x4*)&W[(k0 + r) * DIM + n0 + c4];
            T[c4 + 0][r] = (_Float16)wv[0];
            T[c4 + 1][r] = (_Float16)wv[1];
            T[c4 + 2][r] = (_Float16)wv[2];
            T[c4 + 3][r] = (_Float16)wv[3];
        }
        __syncthreads();
        const int c2 = (t & 7) * 8;
        #pragma unroll
        for (int p = 0; p < 2; ++p) {
            const int r = (t >> 3) + 32 * p;     // n-local
            *(f16x8*)&WtM[(n0 + r) * DIM + k0 + c2] = *(const f16x8*)&T[r][c2];
        }
    } else {
        const int bid = blockIdx.x + 12 * blockIdx.y;  // 0..143
        const int mat = bid / 48;
        const int off = (bid - mat * 48) * 2048 + t * 8;
        const float* src = (mat == 0) ? v : (mat == 1) ? q : a;
        _Float16* dst    = (mat == 0) ? vI : (mat == 1) ? qI : aI;
        f32x4 lo = *(const f32x4*)&src[off];
        f32x4 hi = *(const f32x4*)&src[off + 4];
        f16x8 o;
        o[0] = (_Float16)lo[0]; o[1] = (_Float16)lo[1];
        o[2] = (_Float16)lo[2]; o[3] = (_Float16)lo[3];
        o[4] = (_Float16)hi[0]; o[5] = (_Float16)hi[1];
        o[6] = (_Float16)hi[2]; o[7] = (_Float16)hi[3];
        *(f16x8*)&dst[off] = o;
    }
}

// ---------------- projection GEMM: 1 wave = 16x16 tile, LDS-free -----------
// C[128,768] = A[128,768]@W + b. A f16 row-major, W pre-transposed f16 [n][k].
// grid (8 m-tiles, 48 n-tiles, 3 matrices), 64 threads. 48 independent 16B
// loads fully unrolled -> batched issue; 24 MFMA chain on acc.
__global__ __launch_bounds__(64) void proj_kernel(
    const _Float16* __restrict__ A0, const _Float16* __restrict__ A1, const _Float16* __restrict__ A2,
    const _Float16* __restrict__ T0, const _Float16* __restrict__ T1, const _Float16* __restrict__ T2,
    const float* __restrict__ b0, const float* __restrict__ b1, const float* __restrict__ b2,
    void* __restrict__ C0, void* __restrict__ C1, void* __restrict__ C2,
    int out_f16)
{
    const int mat = blockIdx.z;
    const _Float16* __restrict__ A = (mat == 0) ? A0 : (mat == 1) ? A1 : A2;
    const _Float16* __restrict__ T = (mat == 0) ? T0 : (mat == 1) ? T1 : T2;
    const float* __restrict__ bb   = (mat == 0) ? b0 : (mat == 1) ? b1 : b2;
    void* __restrict__ C           = (mat == 0) ? C0 : (mat == 1) ? C1 : C2;

    const int m0   = blockIdx.x * 16;
    const int n0   = blockIdx.y * 16;
    const int lane = threadIdx.x & 63;
    const int fm   = lane & 15;
    const int fk   = (lane >> 4) << 3;

    const _Float16* pa = A + (m0 + fm) * DIM + fk;
    const _Float16* pb = T + (n0 + fm) * DIM + fk;

    f32x4 acc = (f32x4){0.f, 0.f, 0.f, 0.f};
    #pragma unroll
    for (int s = 0; s < 24; ++s) {
        const f16x8 af = *(const f16x8*)(pa + 32 * s);
        const f16x8 wf = *(const f16x8*)(pb + 32 * s);
        acc = __builtin_amdgcn_mfma_f32_16x16x32_f16(af, wf, acc, 0, 0, 0);
    }

    const int col  = n0 + fm;
    const int row0 = m0 + ((lane >> 4) << 2);
    const float bi = bb[col];
    #pragma unroll
    for (int rr = 0; rr < 4; ++rr) {
        const float val = acc[rr] + bi;
        if (out_f16) ((_Float16*)C)[(row0 + rr) * DIM + col] = (_Float16)val;
        else         ((float*)C)[(row0 + rr) * DIM + col]    = val;
    }
}

// -------- fused MFMA scores + group softmax + marginals + outputs --------
// block = (v-token, head). S[q][a] = sum_k vq[q,k]*ah[a,k], f16 MFMA, both
// operands staged in LDS. wave w == softmax group (q in [32w,32w+32)).
// C layout: col a = at*16+fm; row q'' = qt*16 + quad*4 + rr. No max-sub
// (scores ~N(0,0.17) — exp safe). Epilogue gathers simplify to
// vo[vtok*DIM + h*64 + w*16 + bin] (contiguous).
__global__ __launch_bounds__(256) void fused_attn_kernel(
    const _Float16* __restrict__ vpH, const _Float16* __restrict__ qpH,
    const _Float16* __restrict__ apH,
    const float* __restrict__ vo, const float* __restrict__ qo, const float* __restrict__ ao,
    float* __restrict__ out)
{
    const int vtok = blockIdx.x;   // 0..127
    const int h    = blockIdx.y;   // 0..11

    __shared__ _Float16 vqL[128][72];  // [q][k] f16, pad 72
    __shared__ _Float16 ahL[128][72];  // [a][k] f16

    const int t    = threadIdx.x;
    const int w    = t >> 6;
    const int lane = t & 63;
    const int fm   = lane & 15;
    const int fk   = (lane >> 4) << 3;

    // staging: thread t -> row r = t>>1, k-half kh = (t&1)*32
    {
        const int r  = t >> 1;
        const int kh = (t & 1) << 5;
        const _Float16* pq = qpH + r    * DIM + h * HW + kh;
        const _Float16* pv = vpH + vtok * DIM + h * HW + kh;
        const _Float16* pa = apH + r    * DIM + h * HW + kh;
        #pragma unroll
        for (int u = 0; u < 4; ++u) {
            const f16x8 qv = *(const f16x8*)(pq + 8 * u);
            const f16x8 vv = *(const f16x8*)(pv + 8 * u);
            const f16x8 av = *(const f16x8*)(pa + 8 * u);
            *(f16x8*)&vqL[r][kh + 8 * u] = qv * vv;   // v_pk_mul_f16
            *(f16x8*)&ahL[r][kh + 8 * u] = av;
        }
    }
    __syncthreads();

    f32x4 acc[2][8];
    #pragma unroll
    for (int qt = 0; qt < 2; ++qt)
        #pragma unroll
        for (int at = 0; at < 8; ++at)
            acc[qt][at] = (f32x4){0.f, 0.f, 0.f, 0.f};

    const int q0 = 32 * w;
    #pragma unroll
    for (int ks = 0; ks < 2; ++ks) {
        const f16x8 af0 = *(const f16x8*)&vqL[q0 + fm     ][32 * ks + fk];
        const f16x8 af1 = *(const f16x8*)&vqL[q0 + 16 + fm][32 * ks + fk];
        #pragma unroll
        for (int at = 0; at < 8; ++at) {
            const f16x8 bf = *(const f16x8*)&ahL[16 * at + fm][32 * ks + fk];
            acc[0][at] = __builtin_amdgcn_mfma_f32_16x16x32_f16(af0, bf, acc[0][at], 0, 0, 0);
            acc[1][at] = __builtin_amdgcn_mfma_f32_16x16x32_f16(af1, bf, acc[1][at], 0, 0, 0);
        }
    }

    // exp + marginal partials (no max subtraction).
    // q'' = qt*16 + quad*4 + rr ; a = at*16 + fm
    // v-bin = q''>>1 = qt*8 + quad*2 + (rr>>1) -> sv[qt][rr>>1] (quad in lane)
    // q-bin = (rr&1)*8 + at                    -> sq[rr&1][at]  (lane-uniform)
    // a-bin = fm                               -> sa            (fm in lane)
    float sv[2][2] = {{0.f, 0.f}, {0.f, 0.f}};
    float sq[2][8];
    #pragma unroll
    for (int i = 0; i < 2; ++i)
        #pragma unroll
        for (int j = 0; j < 8; ++j) sq[i][j] = 0.f;
    float sa = 0.f;
    #pragma unroll
    for (int qt = 0; qt < 2; ++qt)
        #pragma unroll
        for (int at = 0; at < 8; ++at)
            #pragma unroll
            for (int rr = 0; rr < 4; ++rr) {
                const float e = __expf(acc[qt][at][rr] * 0.125f);
                sv[qt][rr >> 1] += e;
                sq[rr & 1][at]  += e;
                sa += e;
            }

    // --- reductions (split butterflies; validated R4) ---
    sa += __shfl_xor(sa, 16);
    sa += __shfl_xor(sa, 32);
    float tot = sa;
    tot += __shfl_xor(tot, 1);
    tot += __shfl_xor(tot, 2);
    tot += __shfl_xor(tot, 4);
    tot += __shfl_xor(tot, 8);
    const bool b0 = lane & 1;
    const bool b1 = lane & 2;
    float sF;
    {
        float snd0 = b0 ? sv[0][0] : sv[1][0];
        float snd1 = b0 ? sv[0][1] : sv[1][1];
        float r0 = __shfl_xor(snd0, 1);
        float r1 = __shfl_xor(snd1, 1);
        float s0 = (b0 ? sv[1][0] : sv[0][0]) + r0;   // qt = b0, rh = 0
        float s1 = (b0 ? sv[1][1] : sv[0][1]) + r1;   // qt = b0, rh = 1
        float snd = b1 ? s0 : s1;
        float r2 = __shfl_xor(snd, 2);
        sF = (b1 ? s1 : s0) + r2;                     // qt = b0, rh = b1
    }
    sF += __shfl_xor(sF, 4);
    sF += __shfl_xor(sF, 8);
    float s[16];
    #pragma unroll
    for (int i = 0; i < 2; ++i)
        #pragma unroll
        for (int j = 0; j < 8; ++j) s[i * 8 + j] = sq[i][j];
    #pragma unroll
    for (int k = 0; k < 4; ++k) {
        const int d = 1 << k;
        const int m = 16 >> (k + 1);
        const bool b = (lane >> k) & 1;
        #pragma unroll
        for (int x = 0; x < m; ++x) {
            const float snd = b ? s[x] : s[x + m];
            const float rcv = __shfl_xor(snd, d);
            s[x] = (b ? s[x + m] : s[x]) + rcv;
        }
    }
    s[0] += __shfl_xor(s[0], 16);
    s[0] += __shfl_xor(s[0], 32);

    const int g  = h * 512 + vtok * 4 + w;    // softmax group id
    const int b2 = g / 12;
    const int h2 = g - b2 * 12;
    const float invZ = 1.0f / tot;
    const int obase = vtok * DIM + h * HW + w * 16;   // == fetch_o(., g*16+bin)

    if (fm < 4) {                             // 16 writer lanes: v-outputs
        const int quad = lane >> 4;
        const int bin  = (fm & 1) * 8 + quad * 2 + ((fm >> 1) & 1);
        out[(b2 * 16 + bin) * 12 + h2] = sF * invZ * vo[obase + bin];
    }
    if (lane < 16) {                          // 16 writer lanes: q- and a-outputs
        const int qbin = 8 * (lane & 1) + 4 * ((lane >> 1) & 1)
                       + 2 * ((lane >> 2) & 1) + (lane >> 3);
        out[QOUT_OFF + (b2 * 16 + qbin) * 12 + h2] = s[0] * invZ * qo[obase + qbin];
        out[AOUT_OFF + (b2 * 16 + lane) * 12 + h2] = sa   * invZ * ao[obase + lane];
    }
}

extern "C" void kernel_launch(void* const* d_in, const int* in_sizes, int n_in,
                              void* d_out, int out_size, void* d_ws, size_t ws_size,
                              hipStream_t stream)
{
    const float* v   = (const float*)d_in[0];
    const float* q   = (const float*)d_in[1];
    const float* a   = (const float*)d_in[2];
    // d_in[3..5] = masks, unused by the reference forward
    const float* Wv  = (const float*)d_in[6];
    const float* bv  = (const float*)d_in[7];
    const float* Wq  = (const float*)d_in[8];
    const float* bq  = (const float*)d_in[9];
    const float* Wa  = (const float*)d_in[10];
    const float* ba  = (const float*)d_in[11];
    const float* Wvo = (const float*)d_in[12];
    const float* bvo = (const float*)d_in[13];
    const float* Wqo = (const float*)d_in[14];
    const float* bqo = (const float*)d_in[15];
    const float* Wao = (const float*)d_in[16];
    const float* bao = (const float*)d_in[17];

    float* out = (float*)d_out;

    _Float16* Wt  = (_Float16*)d_ws;             // 6 * 589824 f16
    _Float16* vI  = Wt + 6 * WELEMS;
    _Float16* qI  = vI + PROJ_ELEMS;
    _Float16* aI  = qI + PROJ_ELEMS;
    _Float16* vpH = aI + PROJ_ELEMS;
    _Float16* qpH = vpH + PROJ_ELEMS;
    _Float16* apH = qpH + PROJ_ELEMS;
    float*    vo  = (float*)(apH + PROJ_ELEMS);
    float*    qo  = vo + PROJ_ELEMS;
    float*    ao  = qo + PROJ_ELEMS;

    // 1) transpose+convert weights to f16 [n][k]; convert inputs to f16
    prep_kernel<<<dim3(12, 12, 7), 256, 0, stream>>>(
        v, q, a, Wv, Wq, Wa, Wvo, Wqo, Wao, Wt, vI, qI, aI);
    // 2) stage-1 projections (f16 out)
    proj_kernel<<<dim3(8, 48, 3), 64, 0, stream>>>(
        vI, qI, aI, Wt, Wt + WELEMS, Wt + 2 * WELEMS,
        bv, bq, ba, vpH, qpH, apH, 1);
    // 3) stage-2 projections (f32 out)
    proj_kernel<<<dim3(8, 48, 3), 64, 0, stream>>>(
        vpH, qpH, apH, Wt + 3 * WELEMS, Wt + 4 * WELEMS, Wt + 5 * WELEMS,
        bvo, bqo, bao, vo, qo, ao, 0);
    // 4) fused trilinear scores + grouped softmax + marginal outputs
    fused_attn_kernel<<<dim3(SEQ, NH), 256, 0, stream>>>(
        vpH, qpH, apH, vo, qo, ao, out);
}